// Round 7
// baseline (467.620 us; speedup 1.0000x reference)
//
#include <hip/hip_runtime.h>
#include <hip/hip_bf16.h>

typedef int v4i __attribute__((ext_vector_type(4)));

#define M_DIM 16384
#define N_DIM 4096
#define K_DIM 4096
#define BM 128
#define BN 128
#define BKB 128                 // K-bytes per tile
#define NT (K_DIM / BKB)        // 32 K-tiles

#define QBLK 2048               // quant-x blocks in fused prep
#define PBLK 512                // pack-w blocks in fused prep

// ---- fused pre-pass: grid-partitioned quant(x) || pack(w) (r6, kept) ----
__global__ void prep_kernel(const float4* __restrict__ x, int* __restrict__ qx, int n4x,
                            const int4* __restrict__ w, int* __restrict__ qw, int n4w,
                            const float* __restrict__ act_scale) {
  if (blockIdx.x < QBLK) {
    const float s = fmaxf(act_scale[0], 1e-5f);
    const float inv_s = 1.0f / s;   // r5: reciprocal-multiply (div was VALU-bound)
    int i = blockIdx.x * blockDim.x + threadIdx.x;
    const int stride = QBLK * blockDim.x;
    for (; i < n4x; i += stride) {
      float4 v = x[i];
      int b0 = (int)fminf(fmaxf(rintf(v.x * inv_s), -127.f), 127.f);
      int b1 = (int)fminf(fmaxf(rintf(v.y * inv_s), -127.f), 127.f);
      int b2 = (int)fminf(fmaxf(rintf(v.z * inv_s), -127.f), 127.f);
      int b3 = (int)fminf(fmaxf(rintf(v.w * inv_s), -127.f), 127.f);
      qx[i] = (b0 & 0xff) | ((b1 & 0xff) << 8) | ((b2 & 0xff) << 16) | ((b3 & 0xff) << 24);
    }
  } else {
    int i = (blockIdx.x - QBLK) * blockDim.x + threadIdx.x;
    const int stride = PBLK * blockDim.x;
    for (; i < n4w; i += stride) {
      int4 v = w[i];
      qw[i] = ((v.x - 1) & 0xff) | (((v.y - 1) & 0xff) << 8) |
              (((v.z - 1) & 0xff) << 16) | (((v.w - 1) & 0xff) << 24);
    }
  }
}

// ---- i8 GEMM, r7: 128x128 tile, 4 waves, TWO BLOCKS PER CU.
// r1-r6 established: 256^2 at 256 regs/wave = 1 block/CU = ONE barrier group
// -> 8 waves convoy at each tile barrier, LDS(3072cyc) + MFMA(2611cyc) near-
// serialize at 5344cyc/tile; three scheduling rounds could not break it.
// This round halves the tile so acc=64 regs, ~170 regs/wave, LDS 64KiB/block
// -> 2 blocks/CU. HW round-robins each block's 4 waves across the 4 SIMDs, so
// every SIMD hosts one wave from EACH barrier group: when group A drains at
// its barrier / bursts ds_reads, group B is mid-tile issuing MFMAs (m114
// mechanism; m103 precedent: 128^2 beat 256^2 in simple-barrier loops via
// multi-block occupancy). Per-CU: LDS 192 ops ~ 2304cyc per block-tile-pair
// vs MFMA 1305cyc/SIMD -> LDS-bound ~246us if overlap lands. All verified
// idioms preserved: XOR store/read swizzle formulas (unchanged, constants
// shrink), reg-staging, 1 barrier/tile, bijective XCD swizzle (nwg=4096).
__global__ __launch_bounds__(256, 2) void bitlinear_gemm(
    const signed char* __restrict__ A,   // [M][K] i8
    const signed char* __restrict__ B,   // [N][K] i8
    const float* __restrict__ bias,
    const float* __restrict__ alpha_p,
    const float* __restrict__ act_scale_p,
    float* __restrict__ out) {
  __shared__ __align__(16) signed char As[2][BM * BKB];   // 2 x 16 KiB
  __shared__ __align__(16) signed char Bs[2][BN * BKB];   // 2 x 16 KiB

  const int t = threadIdx.x;
  const int lane = t & 63, wid = t >> 6;
  const int wm = wid >> 1, wn = wid & 1;       // 2M x 2N waves, 64x64 each
  const int l15 = lane & 15, l4 = lane >> 4;

  // XCD-aware bijective swizzle (nwg=4096, divisible by 8)
  const int nwg = (M_DIM / BM) * (N_DIM / BN);   // 128*32 = 4096
  const int wg = (blockIdx.x & 7) * (nwg >> 3) + (blockIdx.x >> 3);
  const int bm = wg / (N_DIM / BN);
  const int bn = wg % (N_DIM / BN);

  // ---- reg-staging addressing: LINEAR global loads, SWIZZLED ds_write ----
  // 256 threads: row-in-unit = t>>3 (0..31), chunk = t&7; units = 32-row panels.
  const signed char* aGl = A + ((size_t)(bm * BM + (t >> 3))) * K_DIM + (t & 7) * 16;
  const signed char* bGl = B + ((size_t)(bn * BN + (t >> 3))) * K_DIM + (t & 7) * 16;
  // LDS write offset: row*128 + (chunk ^ (row&7))*16  (same layout as champion)
  const int wrOff = (t >> 3) * 128 + (((t & 7) ^ ((t >> 3) & 7)) * 16);

  v4i sA[4], sB[4];   // staging registers (one tile in flight)

#define GL_A(u, P) sA[u] = *(const v4i*)((P) + (size_t)((u) * 32) * K_DIM)
#define GL_B(u, P) sB[u] = *(const v4i*)((P) + (size_t)((u) * 32) * K_DIM)
#define WR_A(BUF) { _Pragma("unroll") for (int u = 0; u < 4; ++u) \
    *(v4i*)&As[BUF][u * 4096 + wrOff] = sA[u]; }
#define WR_B(BUF) { _Pragma("unroll") for (int u = 0; u < 4; ++u) \
    *(v4i*)&Bs[BUF][u * 4096 + wrOff] = sB[u]; }

  // ---- fragment read addressing (zero-conflict XOR layout, unchanged) ----
  const int l7 = l15 & 7;
  const int soK0 = ((0 + l4) ^ l7) * 16;   // kstep 0 chunk
  const int soK1 = ((4 + l4) ^ l7) * 16;   // kstep 1 chunk
  const int aRd = (wm * 64 + l15) * BKB;
  const int bRd = (wn * 64 + l15) * BKB;

  v4i acc[4][4] = {};       // [msub][nsub] 16x16 tiles: 64 regs
  v4i bF[4][2], aF[2];

#define LOAD_B(buf) \
  { _Pragma("unroll") for (int nc = 0; nc < 4; ++nc) { \
      bF[nc][0] = *(const v4i*)&Bs[buf][bRd + nc * 2048 + soK0]; \
      bF[nc][1] = *(const v4i*)&Bs[buf][bRd + nc * 2048 + soK1]; } }

#define LOAD_A(buf, m) \
  aF[0] = *(const v4i*)&As[buf][aRd + (m) * 2048 + soK0]; \
  aF[1] = *(const v4i*)&As[buf][aRd + (m) * 2048 + soK1];

#define MFMA_M(m) \
  { _Pragma("unroll") for (int nc = 0; nc < 4; ++nc) { \
      acc[m][nc] = __builtin_amdgcn_mfma_i32_16x16x64_i8(aF[0], bF[nc][0], acc[m][nc], 0, 0, 0); \
      acc[m][nc] = __builtin_amdgcn_mfma_i32_16x16x64_i8(aF[1], bF[nc][1], acc[m][nc], 0, 0, 0); } }

#define BAR __builtin_amdgcn_s_barrier()

  // One K-tile: 4 m-subtiles, no intra-tile barriers, single lgkmcnt(0)+BAR
  // at the buffer flip (champion schedule, scaled down).
#define TILE_BODY(BUF, PA, PB) do { \
    LOAD_B(BUF); LOAD_A(BUF, 0); \
    GL_B(0, PB); GL_B(1, PB); \
    __builtin_amdgcn_s_setprio(1); MFMA_M(0); __builtin_amdgcn_s_setprio(0); \
    LOAD_A(BUF, 1); \
    GL_B(2, PB); GL_B(3, PB); \
    __builtin_amdgcn_s_setprio(1); MFMA_M(1); __builtin_amdgcn_s_setprio(0); \
    LOAD_A(BUF, 2); \
    GL_A(0, PA); GL_A(1, PA); GL_A(2, PA); GL_A(3, PA); \
    __builtin_amdgcn_s_setprio(1); MFMA_M(2); __builtin_amdgcn_s_setprio(0); \
    WR_B(BUF^1); \
    LOAD_A(BUF, 3); \
    __builtin_amdgcn_s_setprio(1); MFMA_M(3); __builtin_amdgcn_s_setprio(0); \
    WR_A(BUF^1); \
    asm volatile("s_waitcnt lgkmcnt(0)" ::: "memory"); \
    BAR; \
  } while (0)

  // ---- prologue: load + write tile 0 ----
  GL_B(0, bGl); GL_B(1, bGl); GL_B(2, bGl); GL_B(3, bGl);
  GL_A(0, aGl); GL_A(1, aGl); GL_A(2, aGl); GL_A(3, aGl);
  asm volatile("s_waitcnt vmcnt(0)" ::: "memory");
  WR_B(0); WR_A(0);
  asm volatile("s_waitcnt lgkmcnt(0)" ::: "memory");
  BAR;
  __builtin_amdgcn_sched_barrier(0);

  // ---- main loop: 2 K-tiles per iteration, compile-time buffer selection ----
  const signed char* aGk = aGl;
  const signed char* bGk = bGl;
  for (int it = 0; it < NT / 2 - 1; ++it) {
    TILE_BODY(0, aGk + BKB,     bGk + BKB);       // tile 2it,   load 2it+1
    TILE_BODY(1, aGk + 2 * BKB, bGk + 2 * BKB);   // tile 2it+1, load 2it+2
    aGk += 2 * BKB; bGk += 2 * BKB;
  }
  TILE_BODY(0, aGk + BKB, bGk + BKB);             // tile 30, load 31
  TILE_BODY(1, aGk + BKB, bGk + BKB);             // tile 31, re-load 31 (dead write to buf0)

  // ---- epilogue: out = acc * (clamped_act_scale * alpha) + bias ----
  const float sA_ = fmaxf(act_scale_p[0], 1e-5f) * alpha_p[0];
  const int gn0 = bn * BN + wn * 64 + l15;
  const int gm0 = bm * BM + wm * 64 + l4 * 4;
#pragma unroll
  for (int nc = 0; nc < 4; ++nc) {
    const float bv = bias[gn0 + nc * 16];
#pragma unroll
    for (int m = 0; m < 4; ++m) {
#pragma unroll
      for (int r = 0; r < 4; ++r) {
        const int gm = gm0 + m * 16 + r;           // C/D: col=lane&15, row=(lane>>4)*4+reg
        out[(size_t)gm * N_DIM + gn0 + nc * 16] = (float)acc[m][nc][r] * sA_ + bv;
      }
    }
  }
}

extern "C" void kernel_launch(void* const* d_in, const int* in_sizes, int n_in,
                              void* d_out, int out_size, void* d_ws, size_t ws_size,
                              hipStream_t stream) {
  const float* x      = (const float*)d_in[0];
  const int*   pw     = (const int*)d_in[1];
  const float* alpha  = (const float*)d_in[2];
  const float* act_sc = (const float*)d_in[3];
  const float* bias   = (const float*)d_in[4];
  float* out = (float*)d_out;

  signed char* x8 = (signed char*)d_ws;                          // 64 MiB
  signed char* w8 = (signed char*)d_ws + (size_t)M_DIM * K_DIM;  // 16 MiB

  prep_kernel<<<QBLK + PBLK, 256, 0, stream>>>(
      (const float4*)x, (int*)x8, M_DIM * K_DIM / 4,
      (const int4*)pw, (int*)w8, N_DIM * K_DIM / 4, act_sc);

  dim3 grid((M_DIM / BM) * (N_DIM / BN));   // 4096 blocks, 1-D for XCD swizzle
  bitlinear_gemm<<<grid, 256, 0, stream>>>(x8, w8, bias, alpha, act_sc, out);
}

// Round 8
// 399.785 us; speedup vs baseline: 1.1697x; 1.1697x over previous
//
#include <hip/hip_runtime.h>
#include <hip/hip_bf16.h>

typedef int v4i __attribute__((ext_vector_type(4)));

#define M_DIM 16384
#define N_DIM 4096
#define K_DIM 4096
#define BM 256
#define BN 256
#define BKB 128                 // K-bytes per tile
#define NT (K_DIM / BKB)        // 32 K-tiles

#define QBLK 2048               // quant-x blocks in fused prep
#define PBLK 512                // pack-w blocks in fused prep

// ---- fused pre-pass: grid-partitioned quant(x) || pack(w) (r6, kept) ----
__global__ void prep_kernel(const float4* __restrict__ x, int* __restrict__ qx, int n4x,
                            const int4* __restrict__ w, int* __restrict__ qw, int n4w,
                            const float* __restrict__ act_scale) {
  if (blockIdx.x < QBLK) {
    const float s = fmaxf(act_scale[0], 1e-5f);
    const float inv_s = 1.0f / s;   // r5: reciprocal-multiply (div was VALU-bound)
    int i = blockIdx.x * blockDim.x + threadIdx.x;
    const int stride = QBLK * blockDim.x;
    for (; i < n4x; i += stride) {
      float4 v = x[i];
      int b0 = (int)fminf(fmaxf(rintf(v.x * inv_s), -127.f), 127.f);
      int b1 = (int)fminf(fmaxf(rintf(v.y * inv_s), -127.f), 127.f);
      int b2 = (int)fminf(fmaxf(rintf(v.z * inv_s), -127.f), 127.f);
      int b3 = (int)fminf(fmaxf(rintf(v.w * inv_s), -127.f), 127.f);
      qx[i] = (b0 & 0xff) | ((b1 & 0xff) << 8) | ((b2 & 0xff) << 16) | ((b3 & 0xff) << 24);
    }
  } else {
    int i = (blockIdx.x - QBLK) * blockDim.x + threadIdx.x;
    const int stride = PBLK * blockDim.x;
    for (; i < n4w; i += stride) {
      int4 v = w[i];
      qw[i] = ((v.x - 1) & 0xff) | (((v.y - 1) & 0xff) << 8) |
              (((v.z - 1) & 0xff) << 16) | (((v.w - 1) & 0xff) << 24);
    }
  }
}

// ---- i8 GEMM, r8: 256^2 REVERTED (r7's 128^2 tripled FETCH: reuse loss >
// overlap gain). Structure quadrant completed: reg-staging+free(285), reg-
// staging+ladder(305), DMA+free(315), DMA+LADDER = this round. Rationale:
// the ladder's r0 cost was the reg-staging chain drained inside phases
// (GL->vmcnt->ds_write->lgkm); DMA staging removes the 64 ds_write_b128
// (-768cyc on the binding LDS pipe), the staging VGPRs, and makes DMAs the
// ONLY vm-counted ops (one clean vmcnt(0)/tile, ~2-phase slack). r3's
// barrier-free DMA regression is attributed to the tile-top DMA burst
// colliding with the un-barriered ph0 read burst; the ladder spreads DMA
// issue (B in ph0, A in ph1) and clusters reads/MFMA per phase (T3+T4
// regime; m218: counted-vmcnt pays ONLY inside the ladder). DMA addressing
// is r3's verified pre-swizzled-source form: stored LDS layout bit-identical
// to the champion's, all fragment-read addressing unchanged.
__global__ __launch_bounds__(512, 2) void bitlinear_gemm(
    const signed char* __restrict__ A,   // [M][K] i8
    const signed char* __restrict__ B,   // [N][K] i8
    const float* __restrict__ bias,
    const float* __restrict__ alpha_p,
    const float* __restrict__ act_scale_p,
    float* __restrict__ out) {
  __shared__ __align__(16) signed char As0[BM * BKB];   // 32 KiB each,
  __shared__ __align__(16) signed char As1[BM * BKB];   // distinct objects
  __shared__ __align__(16) signed char Bs0[BN * BKB];   // (alias precision
  __shared__ __align__(16) signed char Bs1[BN * BKB];   //  for waitcnt pass)

  const int t = threadIdx.x;
  const int lane = t & 63, wid = t >> 6;
  const int wm = wid >> 2, wn = wid & 3;       // 2M x 4N waves
  const int l15 = lane & 15, l4 = lane >> 4;

  // XCD-aware bijective swizzle (nwg=1024, divisible by 8)
  const int nwg = (M_DIM / BM) * (N_DIM / BN);
  const int wg = (blockIdx.x & 7) * (nwg >> 3) + (blockIdx.x >> 3);
  const int bm = wg / (N_DIM / BN);
  const int bn = wg % (N_DIM / BN);

  // ---- DMA staging (r3-verified): wave w owns 4 x 1KiB segments = rows
  // 32w..32w+31. LDS dest linear (base + lane*16); global source pre-swizzled
  // so stored layout == champion layout: lane l -> row 8s+(l>>3), chunk
  // (l&7)^(l>>3).
  const int dmaSeg = wid * 4096;               // LDS byte base of segment 4w
  const signed char* aD = A + ((size_t)(bm * BM + 32 * wid + (lane >> 3))) * K_DIM
                            + (((lane & 7) ^ (lane >> 3)) * 16);
  const signed char* bD = B + ((size_t)(bn * BN + 32 * wid + (lane >> 3))) * K_DIM
                            + (((lane & 7) ^ (lane >> 3)) * 16);

#define DMA4(SRCBASE, DSTARR, KOFF) \
  { _Pragma("unroll") for (int i = 0; i < 4; ++i) \
      __builtin_amdgcn_global_load_lds( \
        (const __attribute__((address_space(1))) void*)((SRCBASE) + (size_t)(8 * i) * K_DIM + (KOFF)), \
        (__attribute__((address_space(3))) void*)(&(DSTARR)[dmaSeg + i * 1024]), \
        16, 0, 0); }

  // ---- fragment read addressing (unchanged champion layout, zero-conflict) ----
  const int l7 = l15 & 7;
  const int soK0 = ((0 + l4) ^ l7) * 16;   // kstep 0 chunk
  const int soK1 = ((4 + l4) ^ l7) * 16;   // kstep 1 chunk
  const int aRd = (wm * 128 + l15) * BKB;
  const int bRd = (wn * 64 + l15) * BKB;

  v4i acc[8][4] = {};
  v4i bF[4][2], aF[2][2];

#define LOAD_B(BS) \
  { _Pragma("unroll") for (int nc = 0; nc < 4; ++nc) { \
      bF[nc][0] = *(const v4i*)&(BS)[bRd + nc * 2048 + soK0]; \
      bF[nc][1] = *(const v4i*)&(BS)[bRd + nc * 2048 + soK1]; } }

#define LOAD_A(AS, q) \
  aF[0][0] = *(const v4i*)&(AS)[aRd + (2*(q)) * 2048 + soK0]; \
  aF[0][1] = *(const v4i*)&(AS)[aRd + (2*(q)) * 2048 + soK1]; \
  aF[1][0] = *(const v4i*)&(AS)[aRd + (2*(q)+1) * 2048 + soK0]; \
  aF[1][1] = *(const v4i*)&(AS)[aRd + (2*(q)+1) * 2048 + soK1];

#define MFMA_Q(q) \
  { _Pragma("unroll") for (int nc = 0; nc < 4; ++nc) { \
      acc[2*(q)][nc]   = __builtin_amdgcn_mfma_i32_16x16x64_i8(aF[0][0], bF[nc][0], acc[2*(q)][nc], 0, 0, 0); \
      acc[2*(q)][nc]   = __builtin_amdgcn_mfma_i32_16x16x64_i8(aF[0][1], bF[nc][1], acc[2*(q)][nc], 0, 0, 0); \
      acc[2*(q)+1][nc] = __builtin_amdgcn_mfma_i32_16x16x64_i8(aF[1][0], bF[nc][0], acc[2*(q)+1][nc], 0, 0, 0); \
      acc[2*(q)+1][nc] = __builtin_amdgcn_mfma_i32_16x16x64_i8(aF[1][1], bF[nc][1], acc[2*(q)+1][nc], 0, 0, 0); } }

#define BAR __builtin_amdgcn_s_barrier()
#define PRIO1 __builtin_amdgcn_s_setprio(1)
#define PRIO0 __builtin_amdgcn_s_setprio(0)

  // One K-tile = 4 phases. Each phase: {ds_read quarter || DMA issue} BAR
  // {MFMA cluster} BAR. Raw s_barrier carries no auto-drain -> DMAs ride
  // across barriers; single vmcnt(0) after MFMA_Q3 (drains 8 DMAs issued
  // 2-3 phases earlier) before the buffer-flip barrier. No lgkm pinning:
  // compiler's counted lgkmcnt for ds_read->MFMA is near-optimal (m97).
#define TILE_BODY(ASR, BSR, ASW, BSW, KNEXT) do { \
    LOAD_B(BSR); LOAD_A(ASR, 0); \
    DMA4(bD, BSW, KNEXT); \
    BAR; \
    PRIO1; MFMA_Q(0); PRIO0; \
    BAR; \
    LOAD_A(ASR, 1); \
    DMA4(aD, ASW, KNEXT); \
    BAR; \
    PRIO1; MFMA_Q(1); PRIO0; \
    BAR; \
    LOAD_A(ASR, 2); \
    BAR; \
    PRIO1; MFMA_Q(2); PRIO0; \
    BAR; \
    LOAD_A(ASR, 3); \
    BAR; \
    PRIO1; MFMA_Q(3); PRIO0; \
    asm volatile("s_waitcnt vmcnt(0)" ::: "memory"); \
    BAR; \
  } while (0)

  // ---- prologue: DMA tile 0 into buf0 ----
  DMA4(bD, Bs0, 0);
  DMA4(aD, As0, 0);
  asm volatile("s_waitcnt vmcnt(0)" ::: "memory");
  BAR;
  __builtin_amdgcn_sched_barrier(0);

  // ---- main loop: 2 K-tiles per iteration, compile-time buffer selection ----
  for (int it = 0; it < NT / 2 - 1; ++it) {
    TILE_BODY(As0, Bs0, As1, Bs1, (2 * it + 1) * BKB);   // tile 2it,   load 2it+1
    TILE_BODY(As1, Bs1, As0, Bs0, (2 * it + 2) * BKB);   // tile 2it+1, load 2it+2
  }
  TILE_BODY(As0, Bs0, As1, Bs1, 31 * BKB);   // tile 30, load 31
  TILE_BODY(As1, Bs1, As0, Bs0, 31 * BKB);   // tile 31, dead re-load (in-bounds)

  // ---- epilogue: out = acc * (clamped_act_scale * alpha) + bias ----
  const float sA_ = fmaxf(act_scale_p[0], 1e-5f) * alpha_p[0];
  const int gn0 = bn * BN + wn * 64 + l15;
  const int gm0 = bm * BM + wm * 128 + l4 * 4;
#pragma unroll
  for (int nc = 0; nc < 4; ++nc) {
    const float bv = bias[gn0 + nc * 16];
#pragma unroll
    for (int mr = 0; mr < 8; ++mr) {
#pragma unroll
      for (int r = 0; r < 4; ++r) {
        const int gm = gm0 + mr * 16 + r;          // C/D: col=lane&15, row=(lane>>4)*4+reg
        out[(size_t)gm * N_DIM + gn0 + nc * 16] = (float)acc[mr][nc][r] * sA_ + bv;
      }
    }
  }
}

extern "C" void kernel_launch(void* const* d_in, const int* in_sizes, int n_in,
                              void* d_out, int out_size, void* d_ws, size_t ws_size,
                              hipStream_t stream) {
  const float* x      = (const float*)d_in[0];
  const int*   pw     = (const int*)d_in[1];
  const float* alpha  = (const float*)d_in[2];
  const float* act_sc = (const float*)d_in[3];
  const float* bias   = (const float*)d_in[4];
  float* out = (float*)d_out;

  signed char* x8 = (signed char*)d_ws;                          // 64 MiB
  signed char* w8 = (signed char*)d_ws + (size_t)M_DIM * K_DIM;  // 16 MiB

  prep_kernel<<<QBLK + PBLK, 256, 0, stream>>>(
      (const float4*)x, (int*)x8, M_DIM * K_DIM / 4,
      (const int4*)pw, (int*)w8, N_DIM * K_DIM / 4, act_sc);

  dim3 grid((M_DIM / BM) * (N_DIM / BN));   // 1024 blocks, 1-D for XCD swizzle
  bitlinear_gemm<<<grid, 512, 0, stream>>>(x8, w8, bias, alpha, act_sc, out);
}

// Round 9
// 362.404 us; speedup vs baseline: 1.2903x; 1.1031x over previous
//
#include <hip/hip_runtime.h>
#include <hip/hip_bf16.h>

typedef int v4i __attribute__((ext_vector_type(4)));

#define M_DIM 16384
#define N_DIM 4096
#define K_DIM 4096
#define BM 256
#define BN 256
#define BKB 128                 // K-bytes per tile
#define NT (K_DIM / BKB)        // 32 K-tiles

#define QBLK 2048               // quant-x blocks in fused prep
#define PBLK 512                // pack-w blocks in fused prep

// ---- fused pre-pass: grid-partitioned quant(x) || pack(w).
// r9: 4 vectors per lane -> one int4 (16B) store. 4x fewer stores and loop
// iterations; the 64B-stride lane reads are L1-absorbed within each wave's
// 4-load cluster. (r5: reciprocal-multiply; r6: fused grid partition.)
__global__ void prep_kernel(const float4* __restrict__ x, int4* __restrict__ qx, int n16x,
                            const int4* __restrict__ w, int4* __restrict__ qw, int n16w,
                            const float* __restrict__ act_scale) {
  if (blockIdx.x < QBLK) {
    const float s = fmaxf(act_scale[0], 1e-5f);
    const float inv_s = 1.0f / s;
#define PKQ(v) (( (int)fminf(fmaxf(rintf((v).x * inv_s), -127.f), 127.f) & 0xff)        | \
               (((int)fminf(fmaxf(rintf((v).y * inv_s), -127.f), 127.f) & 0xff) << 8)  | \
               (((int)fminf(fmaxf(rintf((v).z * inv_s), -127.f), 127.f) & 0xff) << 16) | \
               (((int)fminf(fmaxf(rintf((v).w * inv_s), -127.f), 127.f) & 0xff) << 24))
    int i = blockIdx.x * blockDim.x + threadIdx.x;
    const int stride = QBLK * blockDim.x;
    for (; i < n16x; i += stride) {
      const float4* xp = x + (size_t)i * 4;
      float4 v0 = xp[0], v1 = xp[1], v2 = xp[2], v3 = xp[3];
      int4 o;
      o.x = PKQ(v0); o.y = PKQ(v1); o.z = PKQ(v2); o.w = PKQ(v3);
      qx[i] = o;
    }
  } else {
#define PKW(v) ((((v).x - 1) & 0xff) | ((((v).y - 1) & 0xff) << 8) | \
                ((((v).z - 1) & 0xff) << 16) | ((((v).w - 1) & 0xff) << 24))
    int i = (blockIdx.x - QBLK) * blockDim.x + threadIdx.x;
    const int stride = PBLK * blockDim.x;
    for (; i < n16w; i += stride) {
      const int4* wp = w + (size_t)i * 4;
      int4 v0 = wp[0], v1 = wp[1], v2 = wp[2], v3 = wp[3];
      int4 o;
      o.x = PKW(v0); o.y = PKW(v1); o.z = PKW(v2); o.w = PKW(v3);
      qw[i] = o;
    }
  }
}

// ---- i8 GEMM: r6 champion (285us GEMM, 0 conflicts), unchanged except a
// staging-free TILE_LAST for tile 31 (r6-r8 did a dead 64KiB re-load+write).
// Structure-space verdict after r0-r8: reg-staging+barrier-free 285 |
// reg+ladder 305 | DMA+free 315 | DMA+ladder 312 | 128^2 390 (FETCH 3x) |
// 32x32 297 (conflicts) | A-from-L2 584. Champion mechanisms: compiler-exact
// counted vmcnt on reg-staging GLs; 128x64 wave-tile = per-output LDS-read
// optimum among feasible shapes; 1 barrier/tile; XOR-swizzled LDS (0
// conflicts); bijective XCD swizzle. Register-walled at 1 block/CU; DMA
// killed by conservative waitcnt aliasing (r3/r8 evidence).
__global__ __launch_bounds__(512, 2) void bitlinear_gemm(
    const signed char* __restrict__ A,   // [M][K] i8
    const signed char* __restrict__ B,   // [N][K] i8
    const float* __restrict__ bias,
    const float* __restrict__ alpha_p,
    const float* __restrict__ act_scale_p,
    float* __restrict__ out) {
  __shared__ __align__(16) signed char As[2][BM * BKB];   // 2 x 32 KiB
  __shared__ __align__(16) signed char Bs[2][BN * BKB];   // 2 x 32 KiB

  const int t = threadIdx.x;
  const int lane = t & 63, wid = t >> 6;
  const int wm = wid >> 2, wn = wid & 3;       // 2M x 4N waves
  const int l15 = lane & 15, l4 = lane >> 4;

  // XCD-aware bijective swizzle (nwg=1024, divisible by 8)
  const int nwg = (M_DIM / BM) * (N_DIM / BN);
  const int wg = (blockIdx.x & 7) * (nwg >> 3) + (blockIdx.x >> 3);
  const int bm = wg / (N_DIM / BN);
  const int bn = wg % (N_DIM / BN);

  // ---- reg-staging addressing: LINEAR global loads, SWIZZLED ds_write ----
  const signed char* aGl = A + ((size_t)(bm * BM + (t >> 3))) * K_DIM + (t & 7) * 16;
  const signed char* bGl = B + ((size_t)(bn * BN + (t >> 3))) * K_DIM + (t & 7) * 16;
  // LDS write offset: row*128 + (chunk ^ (row&7))*16
  const int wrOff = (t >> 3) * 128 + (((t & 7) ^ ((t >> 3) & 7)) * 16);

  v4i sA[4], sB[4];   // staging registers (one tile in flight)

#define GL_A(u, P) sA[u] = *(const v4i*)((P) + (size_t)((u) * 64) * K_DIM)
#define GL_B(u, P) sB[u] = *(const v4i*)((P) + (size_t)((u) * 64) * K_DIM)
#define WR_A(BUF) { _Pragma("unroll") for (int u = 0; u < 4; ++u) \
    *(v4i*)&As[BUF][u * 8192 + wrOff] = sA[u]; }
#define WR_B(BUF) { _Pragma("unroll") for (int u = 0; u < 4; ++u) \
    *(v4i*)&Bs[BUF][u * 8192 + wrOff] = sB[u]; }

  // ---- fragment read addressing (zero-conflict XOR layout) ----
  const int l7 = l15 & 7;
  const int soK0 = ((0 + l4) ^ l7) * 16;   // kstep 0 chunk
  const int soK1 = ((4 + l4) ^ l7) * 16;   // kstep 1 chunk
  const int aRd = (wm * 128 + l15) * BKB;
  const int bRd = (wn * 64 + l15) * BKB;

  v4i acc[8][4] = {};
  v4i bF[4][2], aF[2][2];

#define LOAD_B(buf) \
  { _Pragma("unroll") for (int nc = 0; nc < 4; ++nc) { \
      bF[nc][0] = *(const v4i*)&Bs[buf][bRd + nc * 2048 + soK0]; \
      bF[nc][1] = *(const v4i*)&Bs[buf][bRd + nc * 2048 + soK1]; } }

#define LOAD_A(buf, q) \
  aF[0][0] = *(const v4i*)&As[buf][aRd + (2*(q)) * 2048 + soK0]; \
  aF[0][1] = *(const v4i*)&As[buf][aRd + (2*(q)) * 2048 + soK1]; \
  aF[1][0] = *(const v4i*)&As[buf][aRd + (2*(q)+1) * 2048 + soK0]; \
  aF[1][1] = *(const v4i*)&As[buf][aRd + (2*(q)+1) * 2048 + soK1];

#define MFMA_Q(q) \
  { _Pragma("unroll") for (int nc = 0; nc < 4; ++nc) { \
      acc[2*(q)][nc]   = __builtin_amdgcn_mfma_i32_16x16x64_i8(aF[0][0], bF[nc][0], acc[2*(q)][nc], 0, 0, 0); \
      acc[2*(q)][nc]   = __builtin_amdgcn_mfma_i32_16x16x64_i8(aF[0][1], bF[nc][1], acc[2*(q)][nc], 0, 0, 0); \
      acc[2*(q)+1][nc] = __builtin_amdgcn_mfma_i32_16x16x64_i8(aF[1][0], bF[nc][0], acc[2*(q)+1][nc], 0, 0, 0); \
      acc[2*(q)+1][nc] = __builtin_amdgcn_mfma_i32_16x16x64_i8(aF[1][1], bF[nc][1], acc[2*(q)+1][nc], 0, 0, 0); } }

#define BAR __builtin_amdgcn_s_barrier()

  // One K-tile: 4 quarters in program order, no intra-tile barriers; single
  // lgkmcnt(0)+barrier at the buffer flip (verified 285us schedule).
#define TILE_BODY(BUF, PA, PB) do { \
    LOAD_B(BUF); LOAD_A(BUF, 0); \
    GL_B(0, PB); GL_B(1, PB); \
    __builtin_amdgcn_s_setprio(1); MFMA_Q(0); __builtin_amdgcn_s_setprio(0); \
    LOAD_A(BUF, 1); \
    GL_B(2, PB); GL_B(3, PB); \
    __builtin_amdgcn_s_setprio(1); MFMA_Q(1); __builtin_amdgcn_s_setprio(0); \
    LOAD_A(BUF, 2); \
    GL_A(0, PA); GL_A(1, PA); GL_A(2, PA); GL_A(3, PA); \
    __builtin_amdgcn_s_setprio(1); MFMA_Q(2); __builtin_amdgcn_s_setprio(0); \
    WR_B(BUF^1); \
    LOAD_A(BUF, 3); \
    __builtin_amdgcn_s_setprio(1); MFMA_Q(3); __builtin_amdgcn_s_setprio(0); \
    WR_A(BUF^1); \
    asm volatile("s_waitcnt lgkmcnt(0)" ::: "memory"); \
    BAR; \
  } while (0)

  // Final tile: no staging, no flip drain/barrier (epilogue reads no LDS;
  // per-use waits cover the last MFMAs).
#define TILE_LAST(BUF) do { \
    LOAD_B(BUF); LOAD_A(BUF, 0); \
    __builtin_amdgcn_s_setprio(1); MFMA_Q(0); __builtin_amdgcn_s_setprio(0); \
    LOAD_A(BUF, 1); \
    __builtin_amdgcn_s_setprio(1); MFMA_Q(1); __builtin_amdgcn_s_setprio(0); \
    LOAD_A(BUF, 2); \
    __builtin_amdgcn_s_setprio(1); MFMA_Q(2); __builtin_amdgcn_s_setprio(0); \
    LOAD_A(BUF, 3); \
    __builtin_amdgcn_s_setprio(1); MFMA_Q(3); __builtin_amdgcn_s_setprio(0); \
  } while (0)

  // ---- prologue: load + write tile 0 ----
  GL_B(0, bGl); GL_B(1, bGl); GL_B(2, bGl); GL_B(3, bGl);
  GL_A(0, aGl); GL_A(1, aGl); GL_A(2, aGl); GL_A(3, aGl);
  asm volatile("s_waitcnt vmcnt(0)" ::: "memory");
  WR_B(0); WR_A(0);
  asm volatile("s_waitcnt lgkmcnt(0)" ::: "memory");
  BAR;
  __builtin_amdgcn_sched_barrier(0);

  // ---- main loop: 2 K-tiles per iteration, compile-time buffer selection ----
  const signed char* aGk = aGl;
  const signed char* bGk = bGl;
  for (int it = 0; it < NT / 2 - 1; ++it) {
    TILE_BODY(0, aGk + BKB,     bGk + BKB);       // tile 2it,   load 2it+1
    TILE_BODY(1, aGk + 2 * BKB, bGk + 2 * BKB);   // tile 2it+1, load 2it+2
    aGk += 2 * BKB; bGk += 2 * BKB;
  }
  TILE_BODY(0, aGk + BKB, bGk + BKB);             // tile 30, load 31
  TILE_LAST(1);                                   // tile 31, no staging

  // ---- epilogue: out = acc * (clamped_act_scale * alpha) + bias ----
  const float sA_ = fmaxf(act_scale_p[0], 1e-5f) * alpha_p[0];
  const int gn0 = bn * BN + wn * 64 + l15;
  const int gm0 = bm * BM + wm * 128 + l4 * 4;
#pragma unroll
  for (int nc = 0; nc < 4; ++nc) {
    const float bv = bias[gn0 + nc * 16];
#pragma unroll
    for (int mr = 0; mr < 8; ++mr) {
#pragma unroll
      for (int r = 0; r < 4; ++r) {
        const int gm = gm0 + mr * 16 + r;          // C/D: col=lane&15, row=(lane>>4)*4+reg
        out[(size_t)gm * N_DIM + gn0 + nc * 16] = (float)acc[mr][nc][r] * sA_ + bv;
      }
    }
  }
}

extern "C" void kernel_launch(void* const* d_in, const int* in_sizes, int n_in,
                              void* d_out, int out_size, void* d_ws, size_t ws_size,
                              hipStream_t stream) {
  const float* x      = (const float*)d_in[0];
  const int*   pw     = (const int*)d_in[1];
  const float* alpha  = (const float*)d_in[2];
  const float* act_sc = (const float*)d_in[3];
  const float* bias   = (const float*)d_in[4];
  float* out = (float*)d_out;

  signed char* x8 = (signed char*)d_ws;                          // 64 MiB
  signed char* w8 = (signed char*)d_ws + (size_t)M_DIM * K_DIM;  // 16 MiB

  prep_kernel<<<QBLK + PBLK, 256, 0, stream>>>(
      (const float4*)x, (int4*)x8, M_DIM * K_DIM / 16,
      (const int4*)pw, (int4*)w8, N_DIM * K_DIM / 16, act_sc);

  dim3 grid((M_DIM / BM) * (N_DIM / BN));   // 1024 blocks, 1-D for XCD swizzle
  bitlinear_gemm<<<grid, 512, 0, stream>>>(x8, w8, bias, alpha, act_sc, out);
}